// Round 14
// baseline (207.879 us; speedup 1.0000x reference)
//
#include <hip/hip_runtime.h>
#include <hip/hip_bf16.h>
#include <math.h>

#define B_ 64
#define T_ 512
#define D_ 768
#define H_ 96
#define M_ (B_*T_)   // 32768 rows

typedef __attribute__((ext_vector_type(8))) short short8;
typedef __attribute__((ext_vector_type(4))) float f32x4;

__device__ __forceinline__ short f2bf(float f) {
  unsigned u = __float_as_uint(f);
  unsigned r = (u + 0x7FFFu + ((u >> 16) & 1u)) >> 16;   // RTNE
  return (short)r;
}

// ---------------------------------------------------------------------------
// Kernel 0: W -> bf16, transposed to [n][k] (n = mi*96+cc, 288 x 768).
// ---------------------------------------------------------------------------
__global__ __launch_bounds__(256) void wt_kernel(
    const float* __restrict__ Wq, const float* __restrict__ Wk,
    const float* __restrict__ Wv, short* __restrict__ wt)
{
  int id = blockIdx.x * 256 + threadIdx.x;     // 3*96*768 = 221184
  if (id >= 3*H_*D_) return;
  int n = id % 288;
  int k = id / 288;
  int mi = n / 96, cc = n % 96;
  const float* Wm = (mi == 0) ? Wq : ((mi == 1) ? Wk : Wv);
  wt[(size_t)n * D_ + k] = f2bf(Wm[(size_t)k * H_ + cc]);
}

// ---------------------------------------------------------------------------
// Kernel 1: QKV projection — "W-slice resident, barrier-free" structure.
// R13 post-mortem: ALL per-step-staged structures pin at ~58 us because each
// wave reads the whole 288-row B tile per step (144 KB LDS/CU/step > 1100 cyc)
// under a per-step vmcnt(0) barrier.  New structure: block stages a 48-col W
// slice ONCE in fragment-linear LDS (73.7 KB, 2 blocks/CU, ONE barrier in the
// whole kernel); waves grid-stride over 32-row x-stripes with a fully-unrolled
// barrier-free K-loop: A global->reg (3-deep prefetch), B via ds_read_b128 at
// wave-uniform base + lane*16 (ZERO bank conflicts).  x re-read x6 across
// col-groups is L3-absorbed (100 MB < 256 MB).
// ---------------------------------------------------------------------------
#define NGRP 6
#define BPG  85     // blocks per group; grid = 510

__global__ __launch_bounds__(256) void qkv_mfma_kernel(
    const float* __restrict__ x, const short* __restrict__ wt,
    short* __restrict__ qb, short* __restrict__ kb, short* __restrict__ vb)
{
  __shared__ short8 Bs[3 * 24 * 64];   // 73,728 B, fragment-linear

  const int t    = threadIdx.x;
  const int lane = t & 63;
  const int w    = t >> 6;        // 0..3
  const int l15  = lane & 15;
  const int l4   = lane >> 4;
  const int cg   = blockIdx.x / BPG;    // col group 0..5 (cols cg*48..+48)
  const int bg   = blockIdx.x % BPG;    // block within group

  // ---- stage W slice once: Bs[(ci*24+ks)*64+lane] = wt[cg*48+ci*16+(lane&15)][ks*32+(lane>>4)*8]
  for (int idx = t; idx < 3 * 24 * 64; idx += 256) {
    int lidx = idx & 63;
    int ks   = (idx >> 6) % 24;
    int ci   = idx / (24 * 64);
    int row  = cg * 48 + ci * 16 + (lidx & 15);
    int k    = ks * 32 + (lidx >> 4) * 8;
    Bs[idx] = *reinterpret_cast<const short8*>(wt + (size_t)row * D_ + k);
  }
  __syncthreads();     // the ONLY barrier

  const int gw = bg * 4 + w;           // 0..339 wave id within group
  const int mi = cg >> 1;              // matrix (wave-uniform)
  const int c0 = (cg & 1) * 48;        // col offset within matrix
  short* Om = (mi == 0) ? qb : ((mi == 1) ? kb : vb);

  for (int s = gw; s < 1024; s += 340) {     // 32-row stripes
    const int r0 = s * 32;
    const float* xr0 = x + (size_t)(r0 + l15) * D_ + l4 * 8;
    const float* xr1 = x + (size_t)(r0 + 16 + l15) * D_ + l4 * 8;

    f32x4 acc[2][3];
    #pragma unroll
    for (int ri = 0; ri < 2; ++ri)
      #pragma unroll
      for (int ci = 0; ci < 3; ++ci) acc[ri][ci] = (f32x4){0.f, 0.f, 0.f, 0.f};

    // 3-deep A prefetch (48 VGPR)
    float4 p[3][4];
    #pragma unroll
    for (int j = 0; j < 3; ++j) {
      p[j][0] = *reinterpret_cast<const float4*>(xr0 + j * 32);
      p[j][1] = *reinterpret_cast<const float4*>(xr0 + j * 32 + 4);
      p[j][2] = *reinterpret_cast<const float4*>(xr1 + j * 32);
      p[j][3] = *reinterpret_cast<const float4*>(xr1 + j * 32 + 4);
    }

    #pragma unroll
    for (int ks = 0; ks < 24; ++ks) {        // full unroll -> static slot
      const int slot = ks % 3;
      short8 af0, af1;
      af0[0] = f2bf(p[slot][0].x); af0[1] = f2bf(p[slot][0].y);
      af0[2] = f2bf(p[slot][0].z); af0[3] = f2bf(p[slot][0].w);
      af0[4] = f2bf(p[slot][1].x); af0[5] = f2bf(p[slot][1].y);
      af0[6] = f2bf(p[slot][1].z); af0[7] = f2bf(p[slot][1].w);
      af1[0] = f2bf(p[slot][2].x); af1[1] = f2bf(p[slot][2].y);
      af1[2] = f2bf(p[slot][2].z); af1[3] = f2bf(p[slot][2].w);
      af1[4] = f2bf(p[slot][3].x); af1[5] = f2bf(p[slot][3].y);
      af1[6] = f2bf(p[slot][3].z); af1[7] = f2bf(p[slot][3].w);
      if (ks + 3 < 24) {                     // reload slot for step ks+3
        p[slot][0] = *reinterpret_cast<const float4*>(xr0 + (ks + 3) * 32);
        p[slot][1] = *reinterpret_cast<const float4*>(xr0 + (ks + 3) * 32 + 4);
        p[slot][2] = *reinterpret_cast<const float4*>(xr1 + (ks + 3) * 32);
        p[slot][3] = *reinterpret_cast<const float4*>(xr1 + (ks + 3) * 32 + 4);
      }
      #pragma unroll
      for (int ci = 0; ci < 3; ++ci) {
        short8 bf = Bs[(ci * 24 + ks) * 64 + lane];   // uniform base + lane*16
        acc[0][ci] = __builtin_amdgcn_mfma_f32_16x16x32_bf16(af0, bf, acc[0][ci], 0, 0, 0);
        acc[1][ci] = __builtin_amdgcn_mfma_f32_16x16x32_bf16(af1, bf, acc[1][ci], 0, 0, 0);
      }
    }

    // epilogue: frag (ri,ci): rows r0+ri*16+l4*4+reg, col c0+ci*16+l15
    #pragma unroll
    for (int ri = 0; ri < 2; ++ri) {
      int rbase = r0 + ri * 16 + l4 * 4;
      #pragma unroll
      for (int ci = 0; ci < 3; ++ci) {
        int cc = c0 + ci * 16 + l15;
        #pragma unroll
        for (int reg = 0; reg < 4; ++reg)
          Om[(size_t)(rbase + reg) * H_ + cc] = f2bf(acc[ri][ci][reg]);
      }
    }
  }
}

// ---------------------------------------------------------------------------
// Kernel 2: causal flash attention via MFMA bf16 (unchanged from round 13 —
// V arrives row-major, transposed during LDS staging with tok-XOR swizzle).
// ---------------------------------------------------------------------------
#define QB 32
#define KVB 32
#define KSTR 104
#define VSTR 40
#define PSTR 40

__global__ __launch_bounds__(128) void attn_mfma_kernel(
    const short* __restrict__ qb, const short* __restrict__ kb,
    const short* __restrict__ vb, float* __restrict__ out)
{
  __shared__ short ks[KVB][KSTR];     // 6656 B
  __shared__ short vs[H_][VSTR];      // 7680 B
  __shared__ short ps[2][16][PSTR];   // 2560 B

  const int t    = threadIdx.x;
  const int lane = t & 63;
  const int w    = t >> 6;            // 0..1
  const int l15  = lane & 15;
  const int l4   = lane >> 4;
  const int qi   = 15 - blockIdx.x;   // heavy blocks first
  const int b    = blockIdx.y;
  const int q0   = qi * QB;

  short8 qf[3];
  {
    const short* qbase = qb + ((size_t)(b * T_) + q0 + w * 16 + l15) * H_;
    #pragma unroll
    for (int f = 0; f < 3; ++f)
      qf[f] = *reinterpret_cast<const short8*>(qbase + f * 32 + l4 * 8);
  }

  f32x4 acc[6];
  #pragma unroll
  for (int c = 0; c < 6; ++c) acc[c] = (f32x4){0.f, 0.f, 0.f, 0.f};
  float m_r[4] = {-INFINITY, -INFINITY, -INFINITY, -INFINITY};
  float l_r[4] = {0.f, 0.f, 0.f, 0.f};
  const float scale = 0.10206207261596576f;   // 1/sqrt(96)

  const int jmax = q0 + QB;
  for (int j0 = 0; j0 < jmax; j0 += KVB) {
    __syncthreads();
    {  // stage K tile: 32 rows x 96 bf16
      int row = t >> 2, seg = t & 3;
      const short* src = kb + ((size_t)(b * T_) + j0 + row) * H_ + seg * 24;
      short* dst = &ks[row][seg * 24];
      *reinterpret_cast<short8*>(dst)      = *reinterpret_cast<const short8*>(src);
      *reinterpret_cast<short8*>(dst + 8)  = *reinterpret_cast<const short8*>(src + 8);
      *reinterpret_cast<short8*>(dst + 16) = *reinterpret_cast<const short8*>(src + 16);
    }
    {  // stage V tile: transpose 32 tok x 96 h -> vs[h][tokS]
      #pragma unroll
      for (int i = 0; i < 3; ++i) {
        int c = t + i * 128;            // 0..383
        int tok = c / 12;               // 0..31
        int m   = c % 12;               // h-group (h0 = 8m)
        int h0  = m * 8;
        short8 v = *reinterpret_cast<const short8*>(
            vb + (size_t)(b * T_ + j0 + tok) * H_ + h0);
        int tokS = tok ^ ((m & 3) << 3);     // swizzled tok slot
        #pragma unroll
        for (int j = 0; j < 8; ++j) vs[h0 + j][tokS] = v[j];
      }
    }
    __syncthreads();

    f32x4 sfr[2];
    sfr[0] = (f32x4){0.f,0.f,0.f,0.f};
    sfr[1] = (f32x4){0.f,0.f,0.f,0.f};
    #pragma unroll
    for (int ct = 0; ct < 2; ++ct)
      #pragma unroll
      for (int f = 0; f < 3; ++f) {
        short8 kf = *reinterpret_cast<const short8*>(&ks[ct * 16 + l15][f * 32 + l4 * 8]);
        sfr[ct] = __builtin_amdgcn_mfma_f32_16x16x32_bf16(qf[f], kf, sfr[ct], 0, 0, 0);
      }

    const int qrow = q0 + w * 16 + l4 * 4;   // +reg
    float p0[4], p1[4], fsc[4];
    #pragma unroll
    for (int reg = 0; reg < 4; ++reg) {
      float s0 = sfr[0][reg] * scale;
      float s1 = sfr[1][reg] * scale;
      if (j0 + l15      > qrow + reg) s0 = -INFINITY;
      if (j0 + l15 + 16 > qrow + reg) s1 = -INFINITY;
      float tm = fmaxf(s0, s1);
      #pragma unroll
      for (int o = 1; o < 16; o <<= 1) tm = fmaxf(tm, __shfl_xor(tm, o));
      float Mnew = fmaxf(m_r[reg], tm);
      p0[reg] = __expf(s0 - Mnew);
      p1[reg] = __expf(s1 - Mnew);
      float psum = p0[reg] + p1[reg];
      #pragma unroll
      for (int o = 1; o < 16; o <<= 1) psum += __shfl_xor(psum, o);
      fsc[reg] = __expf(m_r[reg] - Mnew);
      m_r[reg] = Mnew;
      l_r[reg] = l_r[reg] * fsc[reg] + psum;
    }
    #pragma unroll
    for (int c = 0; c < 6; ++c)
      #pragma unroll
      for (int reg = 0; reg < 4; ++reg) acc[c][reg] *= fsc[reg];

    #pragma unroll
    for (int reg = 0; reg < 4; ++reg) {
      ps[w][l4 * 4 + reg][l15]      = f2bf(p0[reg]);
      ps[w][l4 * 4 + reg][l15 + 16] = f2bf(p1[reg]);
    }
    short8 pa = *reinterpret_cast<const short8*>(&ps[w][l15][l4 * 8]);

    #pragma unroll
    for (int c = 0; c < 6; ++c) {
      int h = c * 16 + l15;
      short8 vf = *reinterpret_cast<const short8*>(
          &vs[h][(l4 ^ ((h >> 3) & 3)) * 8]);   // un-swizzle tok group
      acc[c] = __builtin_amdgcn_mfma_f32_16x16x32_bf16(pa, vf, acc[c], 0, 0, 0);
    }
  }

  float inv[4];
  #pragma unroll
  for (int reg = 0; reg < 4; ++reg) inv[reg] = 1.f / l_r[reg];
  #pragma unroll
  for (int c = 0; c < 6; ++c) {
    #pragma unroll
    for (int reg = 0; reg < 4; ++reg) {
      size_t row = (size_t)(b * T_) + q0 + w * 16 + l4 * 4 + reg;
      out[row * H_ + c * 16 + l15] = acc[c][reg] * inv[reg];
    }
  }
}

extern "C" void kernel_launch(void* const* d_in, const int* in_sizes, int n_in,
                              void* d_out, int out_size, void* d_ws, size_t ws_size,
                              hipStream_t stream) {
  const float* x  = (const float*)d_in[0];
  const float* Wq = (const float*)d_in[1];
  const float* Wk = (const float*)d_in[2];
  const float* Wv = (const float*)d_in[3];

  short* wt = (short*)d_ws;                                // 442,368 B
  short* qb = (short*)((char*)d_ws + 524288);              // 6,291,456 B
  short* kb = qb + (size_t)M_ * H_;
  short* vb = kb + (size_t)M_ * H_;                        // row-major [M][96]
  float* outp = (float*)d_out;

  hipLaunchKernelGGL(wt_kernel, dim3((3*H_*D_ + 255)/256), dim3(256), 0, stream,
                     Wq, Wk, Wv, wt);
  hipLaunchKernelGGL(qkv_mfma_kernel, dim3(NGRP * BPG), dim3(256), 0, stream,
                     x, wt, qb, kb, vb);
  hipLaunchKernelGGL(attn_mfma_kernel, dim3(T_/QB, B_), dim3(128), 0, stream,
                     qb, kb, vb, outp);
}

// Round 15
// 91.721 us; speedup vs baseline: 2.2664x; 2.2664x over previous
//
#include <hip/hip_runtime.h>
#include <hip/hip_bf16.h>
#include <math.h>

#define B_ 64
#define T_ 512
#define D_ 768
#define H_ 96
#define M_ (B_*T_)   // 32768 rows

typedef __attribute__((ext_vector_type(8))) short short8;
typedef __attribute__((ext_vector_type(4))) float f32x4;

__device__ __forceinline__ short f2bf(float f) {
  unsigned u = __float_as_uint(f);
  unsigned r = (u + 0x7FFFu + ((u >> 16) & 1u)) >> 16;   // RTNE
  return (short)r;
}

__device__ __forceinline__ void gl16(const void* g, void* l) {
  __builtin_amdgcn_global_load_lds(
      (const __attribute__((address_space(1))) unsigned*)g,
      (__attribute__((address_space(3))) unsigned*)l, 16, 0, 0);
}

// ---------------------------------------------------------------------------
// Kernel 0: W -> bf16, transposed to [n][k] (n = mi*96+cc, 288 x 768).
// ---------------------------------------------------------------------------
__global__ __launch_bounds__(256) void wt_kernel(
    const float* __restrict__ Wq, const float* __restrict__ Wk,
    const float* __restrict__ Wv, short* __restrict__ wt)
{
  int id = blockIdx.x * 256 + threadIdx.x;     // 3*96*768 = 221184
  if (id >= 3*H_*D_) return;
  int n = id % 288;
  int k = id / 288;
  int mi = n / 96, cc = n % 96;
  const float* Wm = (mi == 0) ? Wq : ((mi == 1) ? Wk : Wv);
  wt[(size_t)n * D_ + k] = f2bf(Wm[(size_t)k * H_ + cc]);
}

// ---------------------------------------------------------------------------
// Kernel 1: QKV projection — counted-vmcnt pipelined gload_lds GEMM (T3/T4).
// Diagnosis (rounds 6-13): every __syncthreads-per-step structure pins at
// ~5100 cyc/step because the implicit vmcnt(0) drain serializes the freshly
// issued HBM prefetch into the critical path.  Fix: 3 LDS buffers, 2-deep
// prefetch, raw s_barrier + s_waitcnt vmcnt(18) (never 0 in the loop).
// BM=128 x BK=32, 4 waves in 2x2 (wave tile 64x144, acc 4x9).  Exactly 9
// gload_lds per wave per stage (uniform vmcnt).  Swizzle math = round 12.
// ---------------------------------------------------------------------------
#define BMP 128
#define BKP 32
#define ABYTES 16384            // 128 rows x 32 fp32
#define BBYTES 18432            // 288 rows x 32 bf16
#define BUFB (ABYTES + BBYTES)  // 34816

__global__ __launch_bounds__(256, 1) void qkv_mfma_kernel(
    const float* __restrict__ x, const short* __restrict__ wt,
    short* __restrict__ qb, short* __restrict__ kb, short* __restrict__ vb)
{
  __shared__ char LDS[3][BUFB];   // 104,448 B -> 1 block/CU

  const int t    = threadIdx.x;
  const int row0 = blockIdx.x * BMP;
  const int lane = t & 63;
  const int w    = t >> 6;        // 2x2 wave grid
  const int wr   = w >> 1;        // row half: rows wr*64..+64
  const int wc   = w & 1;         // col half: cols wc*144..+144
  const int l15  = lane & 15;
  const int l4   = lane >> 4;

  // stage one K-tile into buffer `base`: 9 gload_lds per wave (uniform).
  // slots 0..15 = A instrs (8 rows x 32 fp32 each); 16..33 = B instrs
  // (16 rows x 32 bf16 each); 34,35 duplicate B instrs 0,1 (benign).
  auto stage = [&](char* base, int k0) {
    #pragma unroll
    for (int i = 0; i < 9; ++i) {
      int slot = w * 9 + i;
      if (slot < 16) {
        int inst = slot;
        int row  = inst * 8 + (lane >> 3);
        int c16  = (lane & 7) ^ ((lane >> 3) & 7);     // pre-swizzled source
        const char* g = (const char*)(x + (size_t)(row0 + row) * D_ + k0) + c16 * 16;
        gl16(g, base + inst * 1024 + lane * 16);
      } else {
        int inst = (slot < 34) ? (slot - 16) : (slot - 34);
        int row  = inst * 16 + (lane >> 2);            // 0..287
        int c16  = (lane & 3) ^ ((lane >> 2) & 3);
        const char* g = (const char*)(wt + (size_t)row * D_ + k0) + c16 * 16;
        gl16(g, base + ABYTES + inst * 1024 + lane * 16);
      }
    }
  };

  f32x4 acc[4][9];
  #pragma unroll
  for (int ri = 0; ri < 4; ++ri)
    #pragma unroll
    for (int ci = 0; ci < 9; ++ci) acc[ri][ci] = (f32x4){0.f, 0.f, 0.f, 0.f};

  auto compute = [&](const char* base) {
    short8 af[4];
    #pragma unroll
    for (int ri = 0; ri < 4; ++ri) {
      int arow = wr * 64 + ri * 16 + l15;
      const char* ab = base + arow * 128;
      float4 a0 = *reinterpret_cast<const float4*>(ab + (((l4 * 2 + 0) ^ (arow & 7)) * 16));
      float4 a1 = *reinterpret_cast<const float4*>(ab + (((l4 * 2 + 1) ^ (arow & 7)) * 16));
      short8 v;
      v[0] = f2bf(a0.x); v[1] = f2bf(a0.y); v[2] = f2bf(a0.z); v[3] = f2bf(a0.w);
      v[4] = f2bf(a1.x); v[5] = f2bf(a1.y); v[6] = f2bf(a1.z); v[7] = f2bf(a1.w);
      af[ri] = v;
    }
    #pragma unroll
    for (int ci = 0; ci < 9; ++ci) {
      int brow = wc * 144 + ci * 16 + l15;
      short8 bf = *reinterpret_cast<const short8*>(
          base + ABYTES + brow * 64 + ((l4 ^ (brow & 3)) * 16));
      #pragma unroll
      for (int ri = 0; ri < 4; ++ri)
        acc[ri][ci] = __builtin_amdgcn_mfma_f32_16x16x32_bf16(af[ri], bf, acc[ri][ci], 0, 0, 0);
    }
  };

  char* b0 = &LDS[0][0];
  char* b1 = &LDS[1][0];
  char* b2 = &LDS[2][0];

  stage(b0, 0);
  stage(b1, BKP);

  for (int ks = 0; ks < 22; ++ks) {
    stage(b2, (ks + 2) * BKP);                         // 9 instrs -> 27 in flight
    asm volatile("s_waitcnt vmcnt(18)" ::: "memory");  // step-ks loads landed
    asm volatile("s_barrier" ::: "memory");            // raw barrier: NO drain
    compute(b0);
    asm volatile("s_barrier" ::: "memory");            // WAR guard for b0 reuse
    char* tmp = b0; b0 = b1; b1 = b2; b2 = tmp;
  }
  // ks = 22 (loads already issued; 18 outstanding)
  asm volatile("s_waitcnt vmcnt(9)" ::: "memory");
  asm volatile("s_barrier" ::: "memory");
  compute(b0);
  // ks = 23
  asm volatile("s_waitcnt vmcnt(0)" ::: "memory");
  asm volatile("s_barrier" ::: "memory");
  compute(b1);

  // epilogue: frag (ri,ci): rows row0+wr*64+ri*16+l4*4+reg, col wc*144+ci*16+l15
  #pragma unroll
  for (int ci = 0; ci < 9; ++ci) {
    int ncol = wc * 144 + ci * 16;
    int mi   = ncol / 96;                 // wave-uniform
    int cc   = ncol % 96 + l15;
    short* Om = (mi == 0) ? qb : ((mi == 1) ? kb : vb);
    #pragma unroll
    for (int ri = 0; ri < 4; ++ri) {
      int rbase = row0 + wr * 64 + ri * 16 + l4 * 4;
      #pragma unroll
      for (int reg = 0; reg < 4; ++reg)
        Om[(size_t)(rbase + reg) * H_ + cc] = f2bf(acc[ri][ci][reg]);
    }
  }
}

// ---------------------------------------------------------------------------
// Kernel 2: causal flash attention via MFMA bf16 (round-13 version, verified).
// ---------------------------------------------------------------------------
#define QB 32
#define KVB 32
#define KSTR 104
#define VSTR 40
#define PSTR 40

__global__ __launch_bounds__(128) void attn_mfma_kernel(
    const short* __restrict__ qb, const short* __restrict__ kb,
    const short* __restrict__ vb, float* __restrict__ out)
{
  __shared__ short ks[KVB][KSTR];     // 6656 B
  __shared__ short vs[H_][VSTR];      // 7680 B
  __shared__ short ps[2][16][PSTR];   // 2560 B

  const int t    = threadIdx.x;
  const int lane = t & 63;
  const int w    = t >> 6;            // 0..1
  const int l15  = lane & 15;
  const int l4   = lane >> 4;
  const int qi   = 15 - blockIdx.x;   // heavy blocks first
  const int b    = blockIdx.y;
  const int q0   = qi * QB;

  short8 qf[3];
  {
    const short* qbase = qb + ((size_t)(b * T_) + q0 + w * 16 + l15) * H_;
    #pragma unroll
    for (int f = 0; f < 3; ++f)
      qf[f] = *reinterpret_cast<const short8*>(qbase + f * 32 + l4 * 8);
  }

  f32x4 acc[6];
  #pragma unroll
  for (int c = 0; c < 6; ++c) acc[c] = (f32x4){0.f, 0.f, 0.f, 0.f};
  float m_r[4] = {-INFINITY, -INFINITY, -INFINITY, -INFINITY};
  float l_r[4] = {0.f, 0.f, 0.f, 0.f};
  const float scale = 0.10206207261596576f;   // 1/sqrt(96)

  const int jmax = q0 + QB;
  for (int j0 = 0; j0 < jmax; j0 += KVB) {
    __syncthreads();
    {  // stage K tile: 32 rows x 96 bf16
      int row = t >> 2, seg = t & 3;
      const short* src = kb + ((size_t)(b * T_) + j0 + row) * H_ + seg * 24;
      short* dst = &ks[row][seg * 24];
      *reinterpret_cast<short8*>(dst)      = *reinterpret_cast<const short8*>(src);
      *reinterpret_cast<short8*>(dst + 8)  = *reinterpret_cast<const short8*>(src + 8);
      *reinterpret_cast<short8*>(dst + 16) = *reinterpret_cast<const short8*>(src + 16);
    }
    {  // stage V tile: transpose 32 tok x 96 h -> vs[h][tokS]
      #pragma unroll
      for (int i = 0; i < 3; ++i) {
        int c = t + i * 128;            // 0..383
        int tok = c / 12;               // 0..31
        int m   = c % 12;               // h-group (h0 = 8m)
        int h0  = m * 8;
        short8 v = *reinterpret_cast<const short8*>(
            vb + (size_t)(b * T_ + j0 + tok) * H_ + h0);
        int tokS = tok ^ ((m & 3) << 3);     // swizzled tok slot
        #pragma unroll
        for (int j = 0; j < 8; ++j) vs[h0 + j][tokS] = v[j];
      }
    }
    __syncthreads();

    f32x4 sfr[2];
    sfr[0] = (f32x4){0.f,0.f,0.f,0.f};
    sfr[1] = (f32x4){0.f,0.f,0.f,0.f};
    #pragma unroll
    for (int ct = 0; ct < 2; ++ct)
      #pragma unroll
      for (int f = 0; f < 3; ++f) {
        short8 kf = *reinterpret_cast<const short8*>(&ks[ct * 16 + l15][f * 32 + l4 * 8]);
        sfr[ct] = __builtin_amdgcn_mfma_f32_16x16x32_bf16(qf[f], kf, sfr[ct], 0, 0, 0);
      }

    const int qrow = q0 + w * 16 + l4 * 4;   // +reg
    float p0[4], p1[4], fsc[4];
    #pragma unroll
    for (int reg = 0; reg < 4; ++reg) {
      float s0 = sfr[0][reg] * scale;
      float s1 = sfr[1][reg] * scale;
      if (j0 + l15      > qrow + reg) s0 = -INFINITY;
      if (j0 + l15 + 16 > qrow + reg) s1 = -INFINITY;
      float tm = fmaxf(s0, s1);
      #pragma unroll
      for (int o = 1; o < 16; o <<= 1) tm = fmaxf(tm, __shfl_xor(tm, o));
      float Mnew = fmaxf(m_r[reg], tm);
      p0[reg] = __expf(s0 - Mnew);
      p1[reg] = __expf(s1 - Mnew);
      float psum = p0[reg] + p1[reg];
      #pragma unroll
      for (int o = 1; o < 16; o <<= 1) psum += __shfl_xor(psum, o);
      fsc[reg] = __expf(m_r[reg] - Mnew);
      m_r[reg] = Mnew;
      l_r[reg] = l_r[reg] * fsc[reg] + psum;
    }
    #pragma unroll
    for (int c = 0; c < 6; ++c)
      #pragma unroll
      for (int reg = 0; reg < 4; ++reg) acc[c][reg] *= fsc[reg];

    #pragma unroll
    for (int reg = 0; reg < 4; ++reg) {
      ps[w][l4 * 4 + reg][l15]      = f2bf(p0[reg]);
      ps[w][l4 * 4 + reg][l15 + 16] = f2bf(p1[reg]);
    }
    short8 pa = *reinterpret_cast<const short8*>(&ps[w][l15][l4 * 8]);

    #pragma unroll
    for (int c = 0; c < 6; ++c) {
      int h = c * 16 + l15;
      short8 vf = *reinterpret_cast<const short8*>(
          &vs[h][(l4 ^ ((h >> 3) & 3)) * 8]);   // un-swizzle tok group
      acc[c] = __builtin_amdgcn_mfma_f32_16x16x32_bf16(pa, vf, acc[c], 0, 0, 0);
    }
  }

  float inv[4];
  #pragma unroll
  for (int reg = 0; reg < 4; ++reg) inv[reg] = 1.f / l_r[reg];
  #pragma unroll
  for (int c = 0; c < 6; ++c) {
    #pragma unroll
    for (int reg = 0; reg < 4; ++reg) {
      size_t row = (size_t)(b * T_) + q0 + w * 16 + l4 * 4 + reg;
      out[row * H_ + c * 16 + l15] = acc[c][reg] * inv[reg];
    }
  }
}

extern "C" void kernel_launch(void* const* d_in, const int* in_sizes, int n_in,
                              void* d_out, int out_size, void* d_ws, size_t ws_size,
                              hipStream_t stream) {
  const float* x  = (const float*)d_in[0];
  const float* Wq = (const float*)d_in[1];
  const float* Wk = (const float*)d_in[2];
  const float* Wv = (const float*)d_in[3];

  short* wt = (short*)d_ws;                                // 442,368 B
  short* qb = (short*)((char*)d_ws + 524288);              // 6,291,456 B
  short* kb = qb + (size_t)M_ * H_;
  short* vb = kb + (size_t)M_ * H_;                        // row-major [M][96]
  float* outp = (float*)d_out;

  hipLaunchKernelGGL(wt_kernel, dim3((3*H_*D_ + 255)/256), dim3(256), 0, stream,
                     Wq, Wk, Wv, wt);
  hipLaunchKernelGGL(qkv_mfma_kernel, dim3(M_/BMP), dim3(256), 0, stream,
                     x, wt, qb, kb, vb);
  hipLaunchKernelGGL(attn_mfma_kernel, dim3(T_/QB, B_), dim3(128), 0, stream,
                     qb, kb, vb, outp);
}

// Round 16
// 79.349 us; speedup vs baseline: 2.6198x; 1.1559x over previous
//
#include <hip/hip_runtime.h>
#include <hip/hip_bf16.h>
#include <math.h>

#define B_ 64
#define T_ 512
#define D_ 768
#define H_ 96
#define M_ (B_*T_)   // 32768 rows

typedef __attribute__((ext_vector_type(8))) short short8;
typedef __attribute__((ext_vector_type(4))) float f32x4;
typedef __attribute__((ext_vector_type(4))) unsigned uint4v;

__device__ __forceinline__ short f2bf(float f) {
  unsigned u = __float_as_uint(f);
  unsigned r = (u + 0x7FFFu + ((u >> 16) & 1u)) >> 16;   // RTNE
  return (short)r;
}

__device__ __forceinline__ unsigned cvtpk(float lo, float hi) {  // 2xf32 -> 2xbf16
  unsigned r;
  asm("v_cvt_pk_bf16_f32 %0, %1, %2" : "=v"(r) : "v"(lo), "v"(hi));
  return r;
}

__device__ __forceinline__ void gl16(const void* g, void* l) {
  __builtin_amdgcn_global_load_lds(
      (const __attribute__((address_space(1))) unsigned*)g,
      (__attribute__((address_space(3))) unsigned*)l, 16, 0, 0);
}

// ---------------------------------------------------------------------------
// Kernel 0: W -> bf16, transposed to [n][k] (n = mi*96+cc, 288 x 768).
// ---------------------------------------------------------------------------
__global__ __launch_bounds__(256) void wt_kernel(
    const float* __restrict__ Wq, const float* __restrict__ Wk,
    const float* __restrict__ Wv, short* __restrict__ wt)
{
  int id = blockIdx.x * 256 + threadIdx.x;     // 3*96*768 = 221184
  if (id >= 3*H_*D_) return;
  int n = id % 288;
  int k = id / 288;
  int mi = n / 96, cc = n % 96;
  const float* Wm = (mi == 0) ? Wq : ((mi == 1) ? Wk : Wv);
  wt[(size_t)n * D_ + k] = f2bf(Wm[(size_t)k * H_ + cc]);
}

// ---------------------------------------------------------------------------
// Kernel 1: QKV projection — R12 gload_lds base + occupancy & VALU levers.
// R15 post-mortem: counted-vmcnt at 1 blk/CU was WORSE (70 us); R8/R9/R12
// triangulation says latency-restructures don't move this kernel; cycle
// count + waves/CU do.  Changes vs R12 (only): (1) BN 288->144, grid (512,2)
// -> LDS 34,816 B -> 4 blocks/CU = 16 waves/CU; (2) A-frag conversion via
// v_cvt_pk_bf16_f32 (4 instrs vs ~32).  Swizzle math byte-identical to R12.
// ---------------------------------------------------------------------------
#define BKP 32
#define ABYTES 8192             // 64 rows x 32 fp32
#define BBYTES 9216             // 144 rows x 32 bf16

__global__ __launch_bounds__(256) void qkv_mfma_kernel(
    const float* __restrict__ x, const short* __restrict__ wt,
    short* __restrict__ qb, short* __restrict__ kb, short* __restrict__ vb)
{
  __shared__ float As[2][64][32];     // 16,384 B
  __shared__ short Bs[2][144][32];    // 18,432 B   (total 34,816)

  const int t    = threadIdx.x;
  const int row0 = blockIdx.x * 64;
  const int cg   = blockIdx.y;        // col group: global cols cg*144..+144
  const int lane = t & 63;
  const int w    = t >> 6;            // wave owns rows [row0+16w, +16)
  const int l15  = lane & 15;
  const int l4   = lane >> 4;

  // ---- staging: global_load_lds, linear LDS dest, pre-swizzled source ----
  auto stageA = [&](int buf, int k0) {
    #pragma unroll
    for (int i = 0; i < 2; ++i) {
      int inst = w * 2 + i;                        // 0..7, 8 rows each
      int row  = inst * 8 + (lane >> 3);
      int c16  = (lane & 7) ^ ((lane >> 3) & 7);
      const char* g = (const char*)(x + (size_t)(row0 + row) * D_ + k0) + c16 * 16;
      char* l = (char*)&As[buf][0][0] + inst * 1024 + lane * 16;
      gl16(g, l);
    }
  };
  auto stageB = [&](int buf, int k0) {
    #pragma unroll
    for (int i = 0; i < 3; ++i) {
      int inst = w + 4 * i;                        // 0..11, guard to 9
      if (inst < 9) {
        int row = inst * 16 + (lane >> 2);         // 0..143 (local)
        int c16 = (lane & 3) ^ ((lane >> 2) & 3);
        const char* g = (const char*)(wt + (size_t)(cg * 144 + row) * D_ + k0) + c16 * 16;
        char* l = (char*)&Bs[buf][0][0] + inst * 1024 + lane * 16;
        gl16(g, l);
      }
    }
  };

  f32x4 acc[9];
  #pragma unroll
  for (int ci = 0; ci < 9; ++ci) acc[ci] = (f32x4){0.f, 0.f, 0.f, 0.f};

  stageA(0, 0);
  stageB(0, 0);
  __syncthreads();

  const int arow = w * 16 + l15;
  const char* Abase = (const char*)&As[0][0][0];
  const char* Bbase = (const char*)&Bs[0][0][0];

  for (int ks = 0; ks < 24; ++ks) {
    int buf = ks & 1;
    if (ks + 1 < 24) { stageA(buf ^ 1, (ks + 1) * BKP); stageB(buf ^ 1, (ks + 1) * BKP); }

    // A-frag: swizzled fp32 read + cvt_pk convert (k = l4*8 .. +8)
    const char* ab = Abase + (size_t)buf * ABYTES + arow * 128;
    float4 a0 = *reinterpret_cast<const float4*>(ab + (((l4 * 2 + 0) ^ (arow & 7)) * 16));
    float4 a1 = *reinterpret_cast<const float4*>(ab + (((l4 * 2 + 1) ^ (arow & 7)) * 16));
    uint4v uv;
    uv[0] = cvtpk(a0.x, a0.y); uv[1] = cvtpk(a0.z, a0.w);
    uv[2] = cvtpk(a1.x, a1.y); uv[3] = cvtpk(a1.z, a1.w);
    short8 af = *reinterpret_cast<short8*>(&uv);

    #pragma unroll
    for (int ci = 0; ci < 9; ++ci) {
      int brow = ci * 16 + l15;                    // local 0..143
      short8 bf = *reinterpret_cast<const short8*>(
          Bbase + (size_t)buf * BBYTES + brow * 64 + ((l4 ^ (brow & 3)) * 16));
      acc[ci] = __builtin_amdgcn_mfma_f32_16x16x32_bf16(af, bf, acc[ci], 0, 0, 0);
    }
    __syncthreads();
  }

  // epilogue: acc[ci]: rows = row0 + w*16 + l4*4 + reg, global col = cg*144+ci*16+l15
  const int rbase = row0 + w * 16 + l4 * 4;
  #pragma unroll
  for (int ci = 0; ci < 9; ++ci) {
    int ncol = cg * 144 + ci * 16;
    int mi   = ncol / 96;                          // wave-uniform
    int cc   = ncol % 96 + l15;
    short* Om = (mi == 0) ? qb : ((mi == 1) ? kb : vb);
    #pragma unroll
    for (int reg = 0; reg < 4; ++reg)
      Om[(size_t)(rbase + reg) * H_ + cc] = f2bf(acc[ci][reg]);
  }
}

// ---------------------------------------------------------------------------
// Kernel 2: causal flash attention via MFMA bf16 (round-13 version, verified).
// ---------------------------------------------------------------------------
#define QB 32
#define KVB 32
#define KSTR 104
#define VSTR 40
#define PSTR 40

__global__ __launch_bounds__(128) void attn_mfma_kernel(
    const short* __restrict__ qb, const short* __restrict__ kb,
    const short* __restrict__ vb, float* __restrict__ out)
{
  __shared__ short ks[KVB][KSTR];     // 6656 B
  __shared__ short vs[H_][VSTR];      // 7680 B
  __shared__ short ps[2][16][PSTR];   // 2560 B

  const int t    = threadIdx.x;
  const int lane = t & 63;
  const int w    = t >> 6;            // 0..1
  const int l15  = lane & 15;
  const int l4   = lane >> 4;
  const int qi   = 15 - blockIdx.x;   // heavy blocks first
  const int b    = blockIdx.y;
  const int q0   = qi * QB;

  short8 qf[3];
  {
    const short* qbase = qb + ((size_t)(b * T_) + q0 + w * 16 + l15) * H_;
    #pragma unroll
    for (int f = 0; f < 3; ++f)
      qf[f] = *reinterpret_cast<const short8*>(qbase + f * 32 + l4 * 8);
  }

  f32x4 acc[6];
  #pragma unroll
  for (int c = 0; c < 6; ++c) acc[c] = (f32x4){0.f, 0.f, 0.f, 0.f};
  float m_r[4] = {-INFINITY, -INFINITY, -INFINITY, -INFINITY};
  float l_r[4] = {0.f, 0.f, 0.f, 0.f};
  const float scale = 0.10206207261596576f;   // 1/sqrt(96)

  const int jmax = q0 + QB;
  for (int j0 = 0; j0 < jmax; j0 += KVB) {
    __syncthreads();
    {  // stage K tile: 32 rows x 96 bf16
      int row = t >> 2, seg = t & 3;
      const short* src = kb + ((size_t)(b * T_) + j0 + row) * H_ + seg * 24;
      short* dst = &ks[row][seg * 24];
      *reinterpret_cast<short8*>(dst)      = *reinterpret_cast<const short8*>(src);
      *reinterpret_cast<short8*>(dst + 8)  = *reinterpret_cast<const short8*>(src + 8);
      *reinterpret_cast<short8*>(dst + 16) = *reinterpret_cast<const short8*>(src + 16);
    }
    {  // stage V tile: transpose 32 tok x 96 h -> vs[h][tokS]
      #pragma unroll
      for (int i = 0; i < 3; ++i) {
        int c = t + i * 128;            // 0..383
        int tok = c / 12;               // 0..31
        int m   = c % 12;               // h-group (h0 = 8m)
        int h0  = m * 8;
        short8 v = *reinterpret_cast<const short8*>(
            vb + (size_t)(b * T_ + j0 + tok) * H_ + h0);
        int tokS = tok ^ ((m & 3) << 3);     // swizzled tok slot
        #pragma unroll
        for (int j = 0; j < 8; ++j) vs[h0 + j][tokS] = v[j];
      }
    }
    __syncthreads();

    f32x4 sfr[2];
    sfr[0] = (f32x4){0.f,0.f,0.f,0.f};
    sfr[1] = (f32x4){0.f,0.f,0.f,0.f};
    #pragma unroll
    for (int ct = 0; ct < 2; ++ct)
      #pragma unroll
      for (int f = 0; f < 3; ++f) {
        short8 kf = *reinterpret_cast<const short8*>(&ks[ct * 16 + l15][f * 32 + l4 * 8]);
        sfr[ct] = __builtin_amdgcn_mfma_f32_16x16x32_bf16(qf[f], kf, sfr[ct], 0, 0, 0);
      }

    const int qrow = q0 + w * 16 + l4 * 4;   // +reg
    float p0[4], p1[4], fsc[4];
    #pragma unroll
    for (int reg = 0; reg < 4; ++reg) {
      float s0 = sfr[0][reg] * scale;
      float s1 = sfr[1][reg] * scale;
      if (j0 + l15      > qrow + reg) s0 = -INFINITY;
      if (j0 + l15 + 16 > qrow + reg) s1 = -INFINITY;
      float tm = fmaxf(s0, s1);
      #pragma unroll
      for (int o = 1; o < 16; o <<= 1) tm = fmaxf(tm, __shfl_xor(tm, o));
      float Mnew = fmaxf(m_r[reg], tm);
      p0[reg] = __expf(s0 - Mnew);
      p1[reg] = __expf(s1 - Mnew);
      float psum = p0[reg] + p1[reg];
      #pragma unroll
      for (int o = 1; o < 16; o <<= 1) psum += __shfl_xor(psum, o);
      fsc[reg] = __expf(m_r[reg] - Mnew);
      m_r[reg] = Mnew;
      l_r[reg] = l_r[reg] * fsc[reg] + psum;
    }
    #pragma unroll
    for (int c = 0; c < 6; ++c)
      #pragma unroll
      for (int reg = 0; reg < 4; ++reg) acc[c][reg] *= fsc[reg];

    #pragma unroll
    for (int reg = 0; reg < 4; ++reg) {
      ps[w][l4 * 4 + reg][l15]      = f2bf(p0[reg]);
      ps[w][l4 * 4 + reg][l15 + 16] = f2bf(p1[reg]);
    }
    short8 pa = *reinterpret_cast<const short8*>(&ps[w][l15][l4 * 8]);

    #pragma unroll
    for (int c = 0; c < 6; ++c) {
      int h = c * 16 + l15;
      short8 vf = *reinterpret_cast<const short8*>(
          &vs[h][(l4 ^ ((h >> 3) & 3)) * 8]);   // un-swizzle tok group
      acc[c] = __builtin_amdgcn_mfma_f32_16x16x32_bf16(pa, vf, acc[c], 0, 0, 0);
    }
  }

  float inv[4];
  #pragma unroll
  for (int reg = 0; reg < 4; ++reg) inv[reg] = 1.f / l_r[reg];
  #pragma unroll
  for (int c = 0; c < 6; ++c) {
    #pragma unroll
    for (int reg = 0; reg < 4; ++reg) {
      size_t row = (size_t)(b * T_) + q0 + w * 16 + l4 * 4 + reg;
      out[row * H_ + c * 16 + l15] = acc[c][reg] * inv[reg];
    }
  }
}

extern "C" void kernel_launch(void* const* d_in, const int* in_sizes, int n_in,
                              void* d_out, int out_size, void* d_ws, size_t ws_size,
                              hipStream_t stream) {
  const float* x  = (const float*)d_in[0];
  const float* Wq = (const float*)d_in[1];
  const float* Wk = (const float*)d_in[2];
  const float* Wv = (const float*)d_in[3];

  short* wt = (short*)d_ws;                                // 442,368 B
  short* qb = (short*)((char*)d_ws + 524288);              // 6,291,456 B
  short* kb = qb + (size_t)M_ * H_;
  short* vb = kb + (size_t)M_ * H_;                        // row-major [M][96]
  float* outp = (float*)d_out;

  hipLaunchKernelGGL(wt_kernel, dim3((3*H_*D_ + 255)/256), dim3(256), 0, stream,
                     Wq, Wk, Wv, wt);
  hipLaunchKernelGGL(qkv_mfma_kernel, dim3(M_/64, 2), dim3(256), 0, stream,
                     x, wt, qb, kb, vb);
  hipLaunchKernelGGL(attn_mfma_kernel, dim3(T_/QB, B_), dim3(128), 0, stream,
                     qb, kb, vb, outp);
}